// Round 4
// baseline (288.138 us; speedup 1.0000x reference)
//
#include <hip/hip_runtime.h>
#include <math.h>

// One wave (64 threads) per batch element; 300-step loop in-kernel.
// Round 4: cross-step software pipeline. Iteration t does:
//   issue pv <- s_p[(t-1)&1] (written a full iteration ago -> no wait)
//   issue zr <- s_z[t&1]
//   encoder(t+1) -> s_z[(t+1)&1]      (hides the LDS read latency)
//   linear+decoder for step t-1       (only s_part round-trip remains, hidden
//                                      by the decoder front half)
//   conv(t) -> s_p[t&1]
// No __syncthreads / fences in the loop: workgroup == 1 wave, DS pipe is
// in-order wave-wide, compiler preserves write->read order via aliasing
// (same structure validated in rounds 2-3). All FP chains keep the exact
// round-3 operation order -> identical numerics.

typedef float v2f __attribute__((ext_vector_type(2)));

#define LDS_FENCE() asm volatile("s_waitcnt lgkmcnt(0)" ::: "memory")

__global__ __launch_bounds__(64) void snn_step_kernel(
    const float* __restrict__ x,       // [B,1,15,15]
    const float* __restrict__ conv_w,  // [2,1,4,4]
    const float* __restrict__ conv_b,  // [2]
    const float* __restrict__ lin_w,   // [10,72]
    const float* __restrict__ lin_b,   // [10]
    float* __restrict__ out,           // spk_out[B,10] ++ mem_rec[T,B,10] ++ spk_rec[T,B,10]
    int T, int B)
{
    const int b = blockIdx.x;
    const int l = threadIdx.x;

    __shared__ float s_convw[32];
    __shared__ float s_convb[2];
    __shared__ float s_linw[720];
    __shared__ float s_linb[10];
    __shared__ float s_z[2][304];   // double-buffered swizzled 15x15 tile (+pad)
    __shared__ float s_p[2][72];    // double-buffered pooled conv outputs
    __shared__ float s_part[64];

    // ---- cooperative weight staging ----
    if (l < 32) s_convw[l] = conv_w[l];
    if (l < 2)  s_convb[l] = conv_b[l];
    for (int j = l; j < 720; j += 64) s_linw[j] = lin_w[j];
    if (l < 10) s_linb[l] = lin_b[l];

    // ---- encoder state: pixels l, l+64, l+128, l+192 (branchless; p>=225 -> pad) ----
    float ve[4], cur[4];
    int   zoff[4];
#pragma unroll
    for (int k = 0; k < 4; ++k) {
        int p = l + 64 * k;
        bool act = (p < 225);
        ve[k]  = 0.0f;
        cur[k] = act ? __fmul_rn(x[(size_t)b * 225 + p], 10.0f) : 0.0f;
        int row = p / 15, col = p - row * 15;
        zoff[k] = row * 16 + col + 3 * (row >> 1);   // swizzle; rows>=15 land in pad (<304)
    }

    // ---- decoder state (lanes 0..9 meaningful) ----
    float v = 0.0f, i_syn = 0.0f, sc = 0.0f;

    // ---- conv lane mapping: lane < 36 -> pooled position (py,px) ----
    const bool convlane = (l < 36);
    const int  py = l / 6, px = l - py * 6;
    const int  wbase = (35 * py + 2 * px) < 229 ? (35 * py + 2 * px) : 229;

    // ---- linear lane mapping: (output lo, quarter lq); weight idx clamped for l>=40 ----
    const int  lo = l >> 2, lq = l & 3;

    const size_t BO = (size_t)B * 10;

    LDS_FENCE();   // staging visible (once, outside the loop)

    // conv weights packed (ch0, ch1) + bias, reused 300x
    v2f wreg2[16];
#pragma unroll
    for (int kk = 0; kk < 16; ++kk) wreg2[kk] = (v2f){s_convw[kk], s_convw[16 + kk]};
    const v2f cb2 = (v2f){s_convb[0], s_convb[1]};

    // linear weights slice into registers (18 per lane, reused 300x)
    float lwreg[18];
#pragma unroll
    for (int j = 0; j < 18; ++j) {
        int idx = lo * 72 + lq * 18 + j;
        lwreg[j] = s_linw[idx < 720 ? idx : 719];
    }
    const float lbias = (l < 10) ? s_linb[l] : 0.0f;

    // incremental output pointers; in loop iter t they point at step t-1
    float* mp  = out + BO + (size_t)b * 10 + l;
    float* spp = out + BO + (size_t)T * BO + (size_t)b * 10 + l;

    // ---- helpers ----
    auto enc_step = [&](float* zbuf) {
#pragma unroll
        for (int k = 0; k < 4; ++k) {
            float vn = __fadd_rn(ve[k], __fmul_rn(0.1f, __fsub_rn(cur[k], ve[k])));
            bool  sp = (vn > 1.0f);
            ve[k] = sp ? 0.0f : vn;
            zbuf[zoff[k]] = sp ? 1.0f : 0.0f;
        }
    };

    const int roff[5] = {0, 16, 35, 51, 70};

    auto conv_step = [&](const float zr[25], float* pbuf) {
        if (convlane) {
            v2f m2 = (v2f){-INFINITY, -INFINITY};
#pragma unroll
            for (int dy = 0; dy < 2; ++dy)
#pragma unroll
                for (int dx = 0; dx < 2; ++dx) {
                    v2f acc = (v2f){0.0f, 0.0f};
#pragma unroll
                    for (int ky = 0; ky < 4; ++ky)
#pragma unroll
                        for (int kx = 0; kx < 4; ++kx) {
                            float z = zr[(dy + ky) * 5 + (dx + kx)];
                            acc = __builtin_elementwise_fma(wreg2[ky * 4 + kx],
                                                            (v2f){z, z}, acc);
                        }
                    v2f val = acc + cb2;
                    m2 = __builtin_elementwise_max(m2, val);
                }
            pbuf[l]      = m2.x;
            pbuf[36 + l] = m2.y;
        }
    };

    // linear(step s) + decoder(step s) from s_p buffer pb; stores via mp/spp
    auto lin_dec_step = [&](const float* pbuf) {
        float pv[18];
        {
            const float* pp = &pbuf[lq * 18];
#pragma unroll
            for (int j = 0; j < 18; ++j) pv[j] = pp[j];
        }
        float partial = 0.0f;
#pragma unroll
        for (int j = 0; j < 18; ++j)
            partial = fmaf(lwreg[j], pv[j], partial);
        s_part[l] = partial;

        // decoder front half (independent of lin) hides the s_part round-trip
        float vd  = __fadd_rn(v, __fmul_rn(0.1f, __fsub_rn(i_syn, v)));
        float id  = __fsub_rn(i_syn, __fmul_rn(0.2f, i_syn));
        float spk = (vd > 1.0f) ? 1.0f : 0.0f;
        v = (vd > 1.0f) ? 0.0f : vd;
        sc += spk;
        if (l < 10) {
            *mp  = v;
            *spp = spk;
        }
        mp  += BO;
        spp += BO;

        float4 pr = *(const float4*)&s_part[4 * (l < 10 ? l : 0)];
        float lin = __fadd_rn(__fadd_rn(__fadd_rn(__fadd_rn(pr.x, pr.y), pr.z), pr.w), lbias);
        i_syn = __fadd_rn(id, lin);
    };

    // ---- prologue: enc(0); then iteration t=0 without linear/decoder ----
    enc_step(s_z[0]);
    {
        float zr[25];
        const float* zc = &s_z[0][wbase];
#pragma unroll
        for (int r = 0; r < 5; ++r)
#pragma unroll
            for (int cc = 0; cc < 5; ++cc)
                zr[r * 5 + cc] = zc[roff[r] + cc];
        enc_step(s_z[1]);
        conv_step(zr, s_p[0]);
    }

    // ---- main loop: iter t does linear/decoder(t-1), enc(t+1), conv(t) ----
    for (int t = 1; t < T; ++t) {
        const int cb = t & 1, pb = cb ^ 1;

        // issue linear-source reads (written a full iteration ago: no wait)
        float pv0[18];
        {
            const float* pp = &s_p[pb][lq * 18];
#pragma unroll
            for (int j = 0; j < 18; ++j) pv0[j] = pp[j];
        }
        // issue conv window reads
        float zr[25];
        {
            const float* zc = &s_z[cb][wbase];
#pragma unroll
            for (int r = 0; r < 5; ++r)
#pragma unroll
                for (int cc = 0; cc < 5; ++cc)
                    zr[r * 5 + cc] = zc[roff[r] + cc];
        }

        // encoder for step t+1 (hides the read latency)
        enc_step(s_z[pb]);

        // linear + decoder for step t-1 (uses pv0, already in flight)
        {
            float partial = 0.0f;
#pragma unroll
            for (int j = 0; j < 18; ++j)
                partial = fmaf(lwreg[j], pv0[j], partial);
            s_part[l] = partial;

            float vd  = __fadd_rn(v, __fmul_rn(0.1f, __fsub_rn(i_syn, v)));
            float id  = __fsub_rn(i_syn, __fmul_rn(0.2f, i_syn));
            float spk = (vd > 1.0f) ? 1.0f : 0.0f;
            v = (vd > 1.0f) ? 0.0f : vd;
            sc += spk;
            if (l < 10) {
                *mp  = v;
                *spp = spk;
            }
            mp  += BO;
            spp += BO;

            float4 pr = *(const float4*)&s_part[4 * (l < 10 ? l : 0)];
            float lin = __fadd_rn(__fadd_rn(__fadd_rn(__fadd_rn(pr.x, pr.y), pr.z), pr.w), lbias);
            i_syn = __fadd_rn(id, lin);
        }

        // conv for step t
        conv_step(zr, s_p[cb]);
    }

    // ---- epilogue: linear + decoder for step T-1 ----
    lin_dec_step(s_p[(T - 1) & 1]);

    if (l < 10) out[(size_t)b * 10 + l] = sc;
}

extern "C" void kernel_launch(void* const* d_in, const int* in_sizes, int n_in,
                              void* d_out, int out_size, void* d_ws, size_t ws_size,
                              hipStream_t stream) {
    const float* x      = (const float*)d_in[0];
    const float* conv_w = (const float*)d_in[1];
    const float* conv_b = (const float*)d_in[2];
    const float* lin_w  = (const float*)d_in[3];
    const float* lin_b  = (const float*)d_in[4];
    float* out = (float*)d_out;

    const int B = in_sizes[0] / 225;             // x is [B,1,15,15]
    const int T = (out_size / (B * 10) - 1) / 2; // out = B*10 * (1 + 2T)

    snn_step_kernel<<<B, 64, 0, stream>>>(x, conv_w, conv_b, lin_w, lin_b, out, T, B);
}

// Round 5
// 263.869 us; speedup vs baseline: 1.0920x; 1.0920x over previous
//
#include <hip/hip_runtime.h>
#include <math.h>

// Round 5: two specialized waves per batch element (block=128).
//   wave0 (tid 0..63):  encoder LIF + conv4x4/maxpool  -> s_p[t&1]
//   wave1 (tid 64..127): linear 72->10 + decoder LIF + global stores,
//                        pipelined ONE STEP BEHIND wave0 (reads s_p[(t-1)&1])
// One __syncthreads per step keeps the two waves in lockstep +-1 step; the
// double-buffered s_p makes the handoff race-free. 4096 waves total -> 4
// waves/SIMD (vs 2 before) to hide LDS/issue stalls. All FP chains are
// byte-identical to round 4 -> numerics unchanged.

typedef float v2f __attribute__((ext_vector_type(2)));

__global__ __launch_bounds__(128) void snn_step_kernel(
    const float* __restrict__ x,       // [B,1,15,15]
    const float* __restrict__ conv_w,  // [2,1,4,4]
    const float* __restrict__ conv_b,  // [2]
    const float* __restrict__ lin_w,   // [10,72]
    const float* __restrict__ lin_b,   // [10]
    float* __restrict__ out,           // spk_out[B,10] ++ mem_rec[T,B,10] ++ spk_rec[T,B,10]
    int T, int B)
{
    const int b   = blockIdx.x;
    const int tid = threadIdx.x;
    const int w   = tid & 63;   // lane within wave
    const int wv  = tid >> 6;   // 0 = enc+conv wave, 1 = lin+dec wave

    __shared__ float s_convw[32];
    __shared__ float s_convb[2];
    __shared__ float s_linw[720];
    __shared__ float s_linb[10];
    __shared__ float s_z[2][304];   // wave0-private, double-buffered swizzled 15x15 (+pad)
    __shared__ float s_p[2][72];    // wave0 -> wave1 handoff, double-buffered
    __shared__ float s_part[64];    // wave1-private

    // ---- cooperative weight staging (128 threads) ----
    if (tid < 32) s_convw[tid] = conv_w[tid];
    if (tid < 2)  s_convb[tid] = conv_b[tid];
    for (int j = tid; j < 720; j += 128) s_linw[j] = lin_w[j];
    if (tid < 10) s_linb[tid] = lin_b[tid];
    __syncthreads();

    // ===== wave0 state =====
    float ve[4], cur[4];
    int   zoff[4];
    v2f   wreg2[16];
    v2f   cb2 = (v2f){0.0f, 0.0f};
    int   wbase = 0;
    bool  convlane = false;

    // ===== wave1 state =====
    float lwreg[18];
    float lbias = 0.0f;
    float v = 0.0f, i_syn = 0.0f, sc = 0.0f;
    const int lo = w >> 2, lq = w & 3;
    const size_t BO = (size_t)B * 10;
    float* mp  = out + BO + (size_t)b * 10 + w;
    float* spp = out + BO + (size_t)T * BO + (size_t)b * 10 + w;

    if (wv == 0) {
        // encoder: lane w owns pixels w, w+64, w+128, w+192 (branchless; p>=225 -> pad)
#pragma unroll
        for (int k = 0; k < 4; ++k) {
            int p = w + 64 * k;
            bool act = (p < 225);
            ve[k]  = 0.0f;
            cur[k] = act ? __fmul_rn(x[(size_t)b * 225 + p], 10.0f) : 0.0f;
            int row = p / 15, col = p - row * 15;
            zoff[k] = row * 16 + col + 3 * (row >> 1);   // swizzle; rows>=15 land in pad
        }
        convlane = (w < 36);
        int py = w / 6, px = w - py * 6;
        int wb = 35 * py + 2 * px;
        wbase = wb < 229 ? wb : 229;   // clamp keeps dead lanes in-bounds
#pragma unroll
        for (int kk = 0; kk < 16; ++kk) wreg2[kk] = (v2f){s_convw[kk], s_convw[16 + kk]};
        cb2 = (v2f){s_convb[0], s_convb[1]};

        // prologue: enc(0) -> s_z[0]
#pragma unroll
        for (int k = 0; k < 4; ++k) {
            float vn = __fadd_rn(ve[k], __fmul_rn(0.1f, __fsub_rn(cur[k], ve[k])));
            bool  sp = (vn > 1.0f);
            ve[k] = sp ? 0.0f : vn;
            s_z[0][zoff[k]] = sp ? 1.0f : 0.0f;
        }
    } else {
#pragma unroll
        for (int j = 0; j < 18; ++j) {
            int idx = lo * 72 + lq * 18 + j;
            lwreg[j] = s_linw[idx < 720 ? idx : 719];   // clamp for lanes >= 40
        }
        lbias = (w < 10) ? s_linb[w] : 0.0f;
    }

    // wave1: linear+decoder for step s from s_p[s&1] (byte-identical to round 4)
    auto lin_dec = [&](const float* pbuf) {
        const float* pp = &pbuf[lq * 18];
        float pv[18];
#pragma unroll
        for (int j = 0; j < 18; ++j) pv[j] = pp[j];
        float partial = 0.0f;
#pragma unroll
        for (int j = 0; j < 18; ++j)
            partial = fmaf(lwreg[j], pv[j], partial);
        s_part[w] = partial;

        float vd  = __fadd_rn(v, __fmul_rn(0.1f, __fsub_rn(i_syn, v)));
        float id  = __fsub_rn(i_syn, __fmul_rn(0.2f, i_syn));
        float spk = (vd > 1.0f) ? 1.0f : 0.0f;
        v = (vd > 1.0f) ? 0.0f : vd;
        sc += spk;
        if (w < 10) {
            *mp  = v;
            *spp = spk;
        }
        mp  += BO;
        spp += BO;

        float4 pr = *(const float4*)&s_part[4 * (w < 10 ? w : 0)];
        float lin = __fadd_rn(__fadd_rn(__fadd_rn(__fadd_rn(pr.x, pr.y), pr.z), pr.w), lbias);
        i_syn = __fadd_rn(id, lin);
    };

    const int roff[5] = {0, 16, 35, 51, 70};

    for (int t = 0; t < T; ++t) {
        const int cb = t & 1;
        if (wv == 0) {
            // issue conv window reads for step t
            float zr[25];
            const float* zc = &s_z[cb][wbase];
#pragma unroll
            for (int r = 0; r < 5; ++r)
#pragma unroll
                for (int cc = 0; cc < 5; ++cc)
                    zr[r * 5 + cc] = zc[roff[r] + cc];

            // encoder for step t+1 (hides the read latency)
#pragma unroll
            for (int k = 0; k < 4; ++k) {
                float vn = __fadd_rn(ve[k], __fmul_rn(0.1f, __fsub_rn(cur[k], ve[k])));
                bool  sp = (vn > 1.0f);
                ve[k] = sp ? 0.0f : vn;
                s_z[cb ^ 1][zoff[k]] = sp ? 1.0f : 0.0f;
            }

            // conv 4x4 (channels packed) + maxpool 2x2 for step t
            if (convlane) {
                v2f m2 = (v2f){-INFINITY, -INFINITY};
#pragma unroll
                for (int dy = 0; dy < 2; ++dy)
#pragma unroll
                    for (int dx = 0; dx < 2; ++dx) {
                        v2f acc = (v2f){0.0f, 0.0f};
#pragma unroll
                        for (int ky = 0; ky < 4; ++ky)
#pragma unroll
                            for (int kx = 0; kx < 4; ++kx) {
                                float z = zr[(dy + ky) * 5 + (dx + kx)];
                                acc = __builtin_elementwise_fma(wreg2[ky * 4 + kx],
                                                                (v2f){z, z}, acc);
                            }
                        v2f val = acc + cb2;
                        m2 = __builtin_elementwise_max(m2, val);
                    }
                s_p[cb][w]      = m2.x;
                s_p[cb][36 + w] = m2.y;
            }
        } else if (t >= 1) {
            // linear + decoder for step t-1 (s_p[(t-1)&1], written before barrier t-1)
            lin_dec(s_p[cb ^ 1]);
        }
        __syncthreads();
    }

    if (wv == 1) {
        lin_dec(s_p[(T - 1) & 1]);               // epilogue: step T-1
        if (w < 10) out[(size_t)b * 10 + w] = sc;
    }
}

extern "C" void kernel_launch(void* const* d_in, const int* in_sizes, int n_in,
                              void* d_out, int out_size, void* d_ws, size_t ws_size,
                              hipStream_t stream) {
    const float* x      = (const float*)d_in[0];
    const float* conv_w = (const float*)d_in[1];
    const float* conv_b = (const float*)d_in[2];
    const float* lin_w  = (const float*)d_in[3];
    const float* lin_b  = (const float*)d_in[4];
    float* out = (float*)d_out;

    const int B = in_sizes[0] / 225;             // x is [B,1,15,15]
    const int T = (out_size / (B * 10) - 1) / 2; // out = B*10 * (1 + 2T)

    snn_step_kernel<<<B, 128, 0, stream>>>(x, conv_w, conv_b, lin_w, lin_b, out, T, B);
}

// Round 6
// 253.738 us; speedup vs baseline: 1.1356x; 1.0399x over previous
//
#include <hip/hip_runtime.h>
#include <math.h>

// Round 6: 4-step-unrolled producer/consumer pipeline, ONE barrier per 4 steps.
//   wave0 (tid 0..63):  enc+conv for steps 4i..4i+3 -> s_p slots (4i+k)&7
//   wave1 (tid 64..127): linear+decoder for steps 4i-4..4i-1 (one iter behind),
//                        global stores DEFERRED one further iteration so the
//                        compiler's vmcnt(0) drain at s_barrier finds them done.
// s_z stays 2-deep (wave0-private, in-order DS pipe orders read(s) before
// enc write(s+2) within the iteration). s_p 8-deep: wave0's live slots
// {4i..4i+3}&7 never collide with wave1's {4i-4..4i-1}&7, and one barrier
// separates write from read. All FP chains byte-identical to round 5.
// Requires T % 4 == 0 (T=300 here).

typedef float v2f __attribute__((ext_vector_type(2)));

__global__ __launch_bounds__(128, 4) void snn_step_kernel(
    const float* __restrict__ x,       // [B,1,15,15]
    const float* __restrict__ conv_w,  // [2,1,4,4]
    const float* __restrict__ conv_b,  // [2]
    const float* __restrict__ lin_w,   // [10,72]
    const float* __restrict__ lin_b,   // [10]
    float* __restrict__ out,           // spk_out[B,10] ++ mem_rec[T,B,10] ++ spk_rec[T,B,10]
    int T, int B)
{
    const int b   = blockIdx.x;
    const int tid = threadIdx.x;
    const int w   = tid & 63;   // lane within wave
    const int wv  = tid >> 6;   // 0 = enc+conv wave, 1 = lin+dec wave

    __shared__ float s_convw[32];
    __shared__ float s_convb[2];
    __shared__ float s_linw[720];
    __shared__ float s_linb[10];
    __shared__ float s_z[2][304];   // wave0-private, double-buffered swizzled 15x15 (+pad)
    __shared__ float s_p[8][72];    // wave0 -> wave1 handoff, 8-deep
    __shared__ float s_part[64];    // wave1-private

    // ---- cooperative weight staging (128 threads) ----
    if (tid < 32) s_convw[tid] = conv_w[tid];
    if (tid < 2)  s_convb[tid] = conv_b[tid];
    for (int j = tid; j < 720; j += 128) s_linw[j] = lin_w[j];
    if (tid < 10) s_linb[tid] = lin_b[tid];
    __syncthreads();

    // ===== wave0 state =====
    float ve[4], cur[4];
    int   zoff[4];
    v2f   wreg2[16];
    v2f   cb2 = (v2f){0.0f, 0.0f};
    int   wbase = 0;
    bool  convlane = false;

    // ===== wave1 state =====
    float lwreg[18];
    float lbias = 0.0f;
    float v = 0.0f, i_syn = 0.0f, sc = 0.0f;
    float svv[4], svs[4];           // deferred store values (v_new, spk) per k
    const int lo = w >> 2, lq = w & 3;
    const size_t BO = (size_t)B * 10;
    float* mp  = out + BO + (size_t)b * 10 + w;
    float* spp = out + BO + (size_t)T * BO + (size_t)b * 10 + w;

    if (wv == 0) {
        // encoder: lane w owns pixels w, w+64, w+128, w+192 (branchless; p>=225 -> pad)
#pragma unroll
        for (int k = 0; k < 4; ++k) {
            int p = w + 64 * k;
            bool act = (p < 225);
            ve[k]  = 0.0f;
            cur[k] = act ? __fmul_rn(x[(size_t)b * 225 + p], 10.0f) : 0.0f;
            int row = p / 15, col = p - row * 15;
            zoff[k] = row * 16 + col + 3 * (row >> 1);   // swizzle; rows>=15 land in pad
        }
        convlane = (w < 36);
        int py = w / 6, px = w - py * 6;
        int wb = 35 * py + 2 * px;
        wbase = wb < 229 ? wb : 229;   // clamp keeps dead lanes in-bounds
#pragma unroll
        for (int kk = 0; kk < 16; ++kk) wreg2[kk] = (v2f){s_convw[kk], s_convw[16 + kk]};
        cb2 = (v2f){s_convb[0], s_convb[1]};

        // prologue: enc(0) -> s_z[0]
#pragma unroll
        for (int k = 0; k < 4; ++k) {
            float vn = __fadd_rn(ve[k], __fmul_rn(0.1f, __fsub_rn(cur[k], ve[k])));
            bool  sp = (vn > 1.0f);
            ve[k] = sp ? 0.0f : vn;
            s_z[0][zoff[k]] = sp ? 1.0f : 0.0f;
        }
    } else {
#pragma unroll
        for (int j = 0; j < 18; ++j) {
            int idx = lo * 72 + lq * 18 + j;
            lwreg[j] = s_linw[idx < 720 ? idx : 719];   // clamp for lanes >= 40
        }
        lbias = (w < 10) ? s_linb[w] : 0.0f;
    }

    // wave1: linear+decoder compute for one step; stores deferred into svv/svs[k]
    auto lin_comp = [&](const float* pbuf, int k) {
        const float* pp = &pbuf[lq * 18];
        float pv[18];
#pragma unroll
        for (int j = 0; j < 18; ++j) pv[j] = pp[j];
        float partial = 0.0f;
#pragma unroll
        for (int j = 0; j < 18; ++j)
            partial = fmaf(lwreg[j], pv[j], partial);
        s_part[w] = partial;

        float vd  = __fadd_rn(v, __fmul_rn(0.1f, __fsub_rn(i_syn, v)));
        float id  = __fsub_rn(i_syn, __fmul_rn(0.2f, i_syn));
        float spk = (vd > 1.0f) ? 1.0f : 0.0f;
        v = (vd > 1.0f) ? 0.0f : vd;
        sc += spk;
        svv[k] = v;
        svs[k] = spk;

        float4 pr = *(const float4*)&s_part[4 * (w < 10 ? w : 0)];
        float lin = __fadd_rn(__fadd_rn(__fadd_rn(__fadd_rn(pr.x, pr.y), pr.z), pr.w), lbias);
        i_syn = __fadd_rn(id, lin);
    };

    auto issue_stores = [&]() {
        if (w < 10) {
#pragma unroll
            for (int k = 0; k < 4; ++k) {
                mp[(size_t)k * BO]  = svv[k];
                spp[(size_t)k * BO] = svs[k];
            }
        }
        mp  += 4 * BO;
        spp += 4 * BO;
    };

    const int roff[5] = {0, 16, 35, 51, 70};
    const int TI = T >> 2;   // T % 4 == 0

    for (int i = 0; i < TI; ++i) {
        if (wv == 0) {
#pragma unroll
            for (int k = 0; k < 4; ++k) {
                // conv window reads for step s=4i+k from s_z[k&1]
                float zr[25];
                const float* zc = &s_z[k & 1][wbase];
#pragma unroll
                for (int r = 0; r < 5; ++r)
#pragma unroll
                    for (int cc = 0; cc < 5; ++cc)
                        zr[r * 5 + cc] = zc[roff[r] + cc];

                // encoder for step s+1 -> s_z[(k+1)&1] (hides read latency)
#pragma unroll
                for (int kk = 0; kk < 4; ++kk) {
                    float vn = __fadd_rn(ve[kk], __fmul_rn(0.1f, __fsub_rn(cur[kk], ve[kk])));
                    bool  sp = (vn > 1.0f);
                    ve[kk] = sp ? 0.0f : vn;
                    s_z[(k + 1) & 1][zoff[kk]] = sp ? 1.0f : 0.0f;
                }

                // conv 4x4 (channels packed) + maxpool 2x2 -> s_p[(4i+k)&7]
                if (convlane) {
                    v2f m2 = (v2f){-INFINITY, -INFINITY};
#pragma unroll
                    for (int dy = 0; dy < 2; ++dy)
#pragma unroll
                        for (int dx = 0; dx < 2; ++dx) {
                            v2f acc = (v2f){0.0f, 0.0f};
#pragma unroll
                            for (int ky = 0; ky < 4; ++ky)
#pragma unroll
                                for (int kx = 0; kx < 4; ++kx) {
                                    float z = zr[(dy + ky) * 5 + (dx + kx)];
                                    acc = __builtin_elementwise_fma(wreg2[ky * 4 + kx],
                                                                    (v2f){z, z}, acc);
                                }
                            v2f val = acc + cb2;
                            m2 = __builtin_elementwise_max(m2, val);
                        }
                    float* pbuf = s_p[((i & 1) << 2) | k];
                    pbuf[w]      = m2.x;
                    pbuf[36 + w] = m2.y;
                }
            }
        } else {
            if (i >= 2) issue_stores();        // steps 4(i-2)..4(i-2)+3
            if (i >= 1) {
#pragma unroll
                for (int k = 0; k < 4; ++k)    // steps 4(i-1)..4(i-1)+3
                    lin_comp(s_p[(((i - 1) & 1) << 2) | k], k);
            }
        }
        __syncthreads();
    }

    // ---- epilogue (wave1): pending stores T-8..T-5, compute+store T-4..T-1 ----
    if (wv == 1) {
        issue_stores();                         // steps T-8..T-5
#pragma unroll
        for (int k = 0; k < 4; ++k)             // steps T-4..T-1
            lin_comp(s_p[(((TI - 1) & 1) << 2) | k], k);
        issue_stores();
        if (w < 10) out[(size_t)b * 10 + w] = sc;
    }
}

extern "C" void kernel_launch(void* const* d_in, const int* in_sizes, int n_in,
                              void* d_out, int out_size, void* d_ws, size_t ws_size,
                              hipStream_t stream) {
    const float* x      = (const float*)d_in[0];
    const float* conv_w = (const float*)d_in[1];
    const float* conv_b = (const float*)d_in[2];
    const float* lin_w  = (const float*)d_in[3];
    const float* lin_b  = (const float*)d_in[4];
    float* out = (float*)d_out;

    const int B = in_sizes[0] / 225;             // x is [B,1,15,15]
    const int T = (out_size / (B * 10) - 1) / 2; // out = B*10 * (1 + 2T); T=300 (div by 4)

    snn_step_kernel<<<B, 128, 0, stream>>>(x, conv_w, conv_b, lin_w, lin_b, out, T, B);
}